// Round 15
// baseline (106.758 us; speedup 1.0000x reference)
//
#include <hip/hip_runtime.h>
#include <hip/hip_bf16.h>

// TransposedLocallyConnected2D: out[b,o,l] = sum_d U[b,d,l] * W[d,l,o] + bias[o,l]
//   B=64, C=64, OC=128, L=1024, D=576 (d = c*9 + ii*3 + jj). Per-l 64x128x576 GEMM.
//
// R15 = R14 + counted-wait k-loop barriers (T4-lite):
//   in-loop __syncthreads() -> s_waitcnt lgkmcnt(0) + raw s_barrier, so the
//   kt+2 W prefetch loads stay in flight across barriers (compiler emits
//   vmcnt(0) at full __syncthreads, serializing load tails into 18 bubbles).
//   LDS deps are fully ordered by lgkmcnt(0)+barrier; W-load->WSTORE dep is
//   compiler-counted vmcnt. Boundary barriers remain full __syncthreads().
// Everything else verbatim R14 (verified): u_kernel 512thr, nontemporal W,
// setprio around MFMA, fragment maps R7-R14, fused epilogue.

typedef __attribute__((ext_vector_type(8))) short bf16x8;
typedef __attribute__((ext_vector_type(4))) float f32x4;
typedef __attribute__((ext_vector_type(4))) unsigned short us4;
typedef __attribute__((ext_vector_type(8))) unsigned short us8;

__device__ __forceinline__ unsigned short f2bf(float f) {
    union { __hip_bfloat16 h; unsigned short u; } cv;
    cv.h = __float2bfloat16(f);
    return cv.u;
}

// ---------------------------------------------------------------- kernel 1
// grid 256 x 512 thr: blk -> ch (c-half), bg (b-quarter = mt), oh.  (R14-verified)
__global__ __launch_bounds__(512, 1)
void u_kernel(const float* __restrict__ x, unsigned short* __restrict__ uA)
{
    __shared__ unsigned short xs[3 * 32 * 16 * 36];   // [y][c][b][32z + 4 pad]

    const int blk = blockIdx.x;
    const int ch = blk & 1;
    const int bg = (blk >> 1) & 3;
    const int oh = blk >> 3;
    const int t  = threadIdx.x;

    #pragma unroll
    for (int y = 0; y < 3; ++y) {
        const int yg = oh - 1 + y;
        const bool rowok = (unsigned)yg < 32u;   // block-uniform
        #pragma unroll
        for (int j = 0; j < 8; ++j) {
            const int idx2 = t + 512 * j;
            const int z4 = idx2 & 7;
            const int cl = (idx2 >> 3) & 31;
            const int bl = idx2 >> 8;
            float4 v = {0.f, 0.f, 0.f, 0.f};
            if (rowok)
                v = *(const float4*)(x + ((((16 * bg + bl) * 64 + 32 * ch + cl) * 32 + yg) << 5) + 4 * z4);
            *(us4*)&xs[((y * 32 + cl) * 16 + bl) * 36 + 4 * z4] =
                (us4){f2bf(v.x), f2bf(v.y), f2bf(v.z), f2bf(v.w)};
        }
    }
    __syncthreads();

    const int bl = t & 15;
    const int ow = t >> 4;
    #pragma unroll
    for (int cc = 0; cc < 2; ++cc) {
        us8 arr[18];
        #pragma unroll
        for (int c16 = 0; c16 < 16; ++c16) {
            const int c = cc * 16 + c16;
            #pragma unroll
            for (int ii = 0; ii < 3; ++ii) {
                const unsigned short* xr = &xs[((ii * 32 + c) * 16 + bl) * 36];
                const unsigned short vm = (ow > 0)  ? xr[ow - 1] : (unsigned short)0;
                const unsigned short v0 = xr[ow];
                const unsigned short vp = (ow < 31) ? xr[ow + 1] : (unsigned short)0;
                const int f = c16 * 9 + ii * 3;      // compile-time after unroll
                arr[(f + 0) >> 3][(f + 0) & 7] = vm;
                arr[(f + 1) >> 3][(f + 1) & 7] = v0;
                arr[(f + 2) >> 3][(f + 2) & 7] = vp;
            }
        }
        char* base = (char*)uA + (size_t)(oh * 4 + bg) * 589824 + (ow * 16 + bl) * 16;
        #pragma unroll
        for (int j = 0; j < 18; ++j) {
            const int ks = 36 * ch + 18 * cc + j;
            *(us8*)(base + (size_t)(ks >> 2) * 32768 + (size_t)(ks & 3) * 8192) = arr[j];
        }
    }
}

// ---------------------------------------------------------------- kernel 2
// grid 512 = (xcd 8, oq 4, hi 16); 512 thr = 8 waves; wave wvn: l = lg8*8 + wvn.
__global__ __launch_bounds__(512, 4)
void mfma_fused(const unsigned short* __restrict__ uA,
                const float* __restrict__ w,
                const float* __restrict__ bias,
                float* __restrict__ out)
{
    __shared__ char smem[36864];   // W dbuf 2x18432B; epilogue Ls (16896B) overlays
    unsigned short* const wb0 = (unsigned short*)smem;
    unsigned short* const wb1 = (unsigned short*)(smem + 18432);

    const int blk  = blockIdx.x;
    const int xcd  = blk & 7;
    const int oq   = (blk >> 3) & 3;     // o0 = 32*oq
    const int hi   = blk >> 5;           // 0..15
    const int lg8  = xcd * 16 + hi;      // 0..127, 8 l's per block
    const int tid  = threadIdx.x;
    const int lane = tid & 63;
    const int wvn  = tid >> 6;           // 0..7 -> l = lg8*8 + wvn
    const int r    = lane & 15;
    const int g    = lane >> 4;
    const int oh   = lg8 >> 2;                   // block-uniform
    const int ow   = ((lg8 & 3) << 3) + wvn;     // l & 31
    const int o0   = 32 * oq;

    // ---- uA addressing (R7-R14 verified cells)
    const char* ubase = (const char*)uA + (size_t)oh * 2359296;
    const unsigned uoff = (unsigned)(g * 8192 + (ow * 16 + r) * 16);

    // ---- W loader: D = tid>>6 (=e), lL = (tid>>3)&7, o4 = tid&7
    const int D  = tid >> 6;
    const int lL = (tid >> 3) & 7;
    const int o4 = tid & 7;
    const float* wth = w + (size_t)D * 131072 + (lg8 * 8 + lL) * 128 + o0 + o4 * 4;

    // slot s = (o4>>2)*64 + rr*16 + rf, rf=(o4&3)*4+v; row = 72 ushorts (144B pad)
#define WSTORE(BUF, RT)                                                        \
    {   _Pragma("unroll")                                                      \
        for (int rr = 0; rr < 4; ++rr) {                                       \
            _Pragma("unroll")                                                  \
            for (int v = 0; v < 4; ++v) {                                      \
                const int s = (o4 >> 2) * 64 + rr * 16 + (o4 & 3) * 4 + v;     \
                (BUF)[s * 72 + lL * 8 + D] = f2bf((RT)[rr][v]);                \
            }                                                                  \
        }                                                                      \
    }
#define WLOAD(KT, RT)                                                          \
    {   _Pragma("unroll")                                                      \
        for (int rr = 0; rr < 4; ++rr)                                         \
            (RT)[rr] = __builtin_nontemporal_load(                             \
                (const f32x4*)(wth + ((size_t)(KT) * 32 + 8 * rr) * 131072));  \
    }
#define ULOAD(KT, CU)                                                          \
    {   _Pragma("unroll")                                                      \
        for (int mt = 0; mt < 4; ++mt)                                         \
            (CU)[mt] = *(const bf16x8*)(ubase + (size_t)(KT) * 32768 +         \
                                        (size_t)mt * 589824 + uoff);           \
    }
    // counted-wait barrier: order LDS ops only; leave W global loads in flight
#define KBAR()                                                                 \
    {   asm volatile("s_waitcnt lgkmcnt(0)" ::: "memory");                     \
        __builtin_amdgcn_s_barrier(); }

    // ---- B-fragment read offsets (ushort units), conflict-free-by-pad
    const int rdo0 = (g * 16 + r) * 72 + wvn * 8;
    const int rdo1 = (64 + g * 16 + r) * 72 + wvn * 8;

    f32x4 acc[4][2];
    #pragma unroll
    for (int mt = 0; mt < 4; ++mt) {
        acc[mt][0] = (f32x4){0.f, 0.f, 0.f, 0.f};
        acc[mt][1] = (f32x4){0.f, 0.f, 0.f, 0.f};
    }

    // ---- prologue: 2 W tiles + 2 uA tiles in flight
    f32x4 rA[4], rB[4];
    bf16x8 cuA[4], cuB[4];
    WLOAD(0, rA);
    WLOAD(1, rB);
    ULOAD(0, cuA);
    ULOAD(1, cuB);
    WSTORE(wb0, rA);
    __syncthreads();

    #pragma unroll
    for (int kt = 0; kt < 18; ++kt) {
        if (kt + 2 < 18) {
            if ((kt & 1) == 0) { WLOAD(kt + 2, rA); }
            else               { WLOAD(kt + 2, rB); }
        }
        if (kt + 1 < 18) {
            if ((kt & 1) == 0) { WSTORE(wb1, rB); }
            else               { WSTORE(wb0, rA); }
        }
        {
            const unsigned short* bb = (kt & 1) ? wb1 : wb0;
            const bf16x8 bf0 = *(const bf16x8*)(bb + rdo0);
            const bf16x8 bf1 = *(const bf16x8*)(bb + rdo1);
            __builtin_amdgcn_s_setprio(1);
            #pragma unroll
            for (int mt = 0; mt < 4; ++mt) {
                const bf16x8 cu = (kt & 1) ? cuB[mt] : cuA[mt];
                acc[mt][0] = __builtin_amdgcn_mfma_f32_16x16x32_bf16(cu, bf0, acc[mt][0], 0, 0, 0);
                acc[mt][1] = __builtin_amdgcn_mfma_f32_16x16x32_bf16(cu, bf1, acc[mt][1], 0, 0, 0);
            }
            __builtin_amdgcn_s_setprio(0);
        }
        if (kt + 2 < 18) {
            if ((kt & 1) == 0) { ULOAD(kt + 2, cuA); }
            else               { ULOAD(kt + 2, cuB); }
        }
        if (kt < 17) { KBAR(); }
        else         { __syncthreads(); }   // full drain before epilogue overlay
    }
#undef WSTORE
#undef WLOAD
#undef ULOAD
#undef KBAR

    // ---- epilogue: 4 mt-phases via LDS [o' 32][l~ 8][b~ 16], row stride 132 f32
    float* const Ls = (float*)smem;
    const int rb = tid & 15;             // b~
    const int ro = tid >> 4;             // o' 0..31
    #pragma unroll
    for (int p = 0; p < 4; ++p) {
        __syncthreads();
        #pragma unroll
        for (int n = 0; n < 2; ++n) {
            const int fidx = (16 * n + r) * 132 + wvn * 16 + 4 * g;
            *(f32x4*)&Ls[fidx] = acc[p][n];
        }
        __syncthreads();
        #pragma unroll
        for (int l4 = 0; l4 < 2; ++l4) {
            f32x4 v;
            #pragma unroll
            for (int j = 0; j < 4; ++j)
                v[j] = Ls[ro * 132 + (l4 * 4 + j) * 16 + rb];
            const int b = 16 * p + rb;
            const int o = o0 + ro;
            const int lbase = lg8 * 8 + l4 * 4;
            const f32x4 bz = *(const f32x4*)(bias + (o << 10) + lbase);
            v += bz;
            *(f32x4*)(out + (((size_t)(b * 128 + o)) << 10) + lbase) = v;
        }
    }
}

// ---------------------------------------------------------------- fp32 fallback (R1-verified)
__global__ __launch_bounds__(256, 4)
void lc2d_fp32(const float* __restrict__ x,
               const float* __restrict__ w,
               const float* __restrict__ bias,
               float* __restrict__ out)
{
    __shared__ float Us[36][68];
    __shared__ float Ws[36][128];
    const int blk = blockIdx.x;
    const int l  = ((blk & 7) << 7) | (blk >> 3);
    const int oh = l >> 5, ow = l & 31;
    const int tid = threadIdx.x;
    const int tx = tid & 15, ty = tid >> 4;
    const int sb = tid >> 2, sc = tid & 3;

    float acc[4][8];
    #pragma unroll
    for (int i = 0; i < 4; ++i)
        #pragma unroll
        for (int j = 0; j < 8; ++j) acc[i][j] = 0.f;

    for (int chn = 0; chn < 16; ++chn) {
        const int c0 = chn * 4;
        const float* xb = x + ((size_t)(sb * 64 + c0 + sc) << 10);
        #pragma unroll
        for (int ii = 0; ii < 3; ++ii) {
            const int y = oh + ii - 1;
            const bool yok = ((unsigned)y < 32u);
            #pragma unroll
            for (int jj = 0; jj < 3; ++jj) {
                const int z = ow + jj - 1;
                float v = 0.f;
                if (yok && ((unsigned)z < 32u)) v = xb[(y << 5) + z];
                Us[sc * 9 + ii * 3 + jj][sb] = v;
            }
        }
        const int dbase = c0 * 9;
        #pragma unroll
        for (int it = 0; it < 5; ++it) {
            const int idx = tid + it * 256;
            if (idx < 36 * 32) {
                const int kk = idx >> 5, o4 = idx & 31;
                const float4 v = *reinterpret_cast<const float4*>(
                    w + (((size_t)(dbase + kk) * 1024 + l) * 128 + o4 * 4));
                *reinterpret_cast<float4*>(&Ws[kk][o4 * 4]) = v;
            }
        }
        __syncthreads();
        #pragma unroll 6
        for (int kk = 0; kk < 36; ++kk) {
            const float4 ub = *reinterpret_cast<const float4*>(&Us[kk][ty * 4]);
            const float4 wa = *reinterpret_cast<const float4*>(&Ws[kk][tx * 4]);
            const float4 wb = *reinterpret_cast<const float4*>(&Ws[kk][tx * 4 + 64]);
            const float u[4]  = {ub.x, ub.y, ub.z, ub.w};
            const float a[4]  = {wa.x, wa.y, wa.z, wa.w};
            const float b2[4] = {wb.x, wb.y, wb.z, wb.w};
            #pragma unroll
            for (int bi = 0; bi < 4; ++bi)
                #pragma unroll
                for (int oi = 0; oi < 4; ++oi) {
                    acc[bi][oi]     += u[bi] * a[oi];
                    acc[bi][4 + oi] += u[bi] * b2[oi];
                }
        }
        __syncthreads();
    }

    float bs[8];
    #pragma unroll
    for (int oi = 0; oi < 4; ++oi) {
        bs[oi]     = bias[((tx * 4 + oi) << 10) + l];
        bs[4 + oi] = bias[((tx * 4 + 64 + oi) << 10) + l];
    }
    #pragma unroll
    for (int bi = 0; bi < 4; ++bi) {
        const int b = ty * 4 + bi;
        #pragma unroll
        for (int oi = 0; oi < 4; ++oi) {
            out[((b * 128 + tx * 4 + oi) << 10) + l]      = acc[bi][oi]     + bs[oi];
            out[((b * 128 + tx * 4 + 64 + oi) << 10) + l] = acc[bi][4 + oi] + bs[4 + oi];
        }
    }
}

// ---------------------------------------------------------------- launch
extern "C" void kernel_launch(void* const* d_in, const int* in_sizes, int n_in,
                              void* d_out, int out_size, void* d_ws, size_t ws_size,
                              hipStream_t stream) {
    const float* x    = (const float*)d_in[0];
    const float* w    = (const float*)d_in[1];
    const float* bias = (const float*)d_in[2];
    float* out        = (float*)d_out;

    const size_t UA_BYTES = 75497472ull;   // 32*4*18*4*8192

    if (d_ws && ws_size >= UA_BYTES) {
        unsigned short* uab = (unsigned short*)d_ws;
        u_kernel<<<dim3(256), dim3(512), 0, stream>>>(x, uab);
        mfma_fused<<<dim3(512), dim3(512), 0, stream>>>(uab, w, bias, out);
    } else {
        lc2d_fp32<<<dim3(1024), dim3(256), 0, stream>>>(x, w, bias, out);
    }
}